// Round 5
// baseline (186.881 us; speedup 1.0000x reference)
//
#include <hip/hip_runtime.h>

// CIN fused 3-layer, bf16 MFMA (R11): R10 structure, register cap lifted.
// cur[sl,n] = sum_f x_f[sl] * S_f[sl,n],  S_f = sum_g h_g[sl] * W[f*64+g, n].
//
// R10 post-mortem: __launch_bounds__(1024,4) -- 2nd arg is CUDA-style min
// BLOCKS/CU -> compiler capped at 64 arch-VGPR (R9 and R10 both report
// exactly 64) while the kernel needs ~100 -> everything spilled to scratch
// (FETCH 69 MB + WRITE 50 MB of spill traffic, 127 us). The ks-split +
// global-xr structure itself was never really benched.
//
// R11:
//  - __launch_bounds__(1024, 1): 136 KB LDS means 1 block/CU regardless;
//    4 waves/SIMD -> 128-VGPR budget. No spill.
//  - All K-loop state in NAMED SCALARS (a0-3, cur0-3, xc0-3, xn0-3): no
//    runtime-indexable arrays (rule #20).
//  - Structure as R10: 16 waves = 8 n-tiles x 2 ks-halves, each wave all
//    4 m-tiles, one un-chained MFMA per (mt,f). B-frag LDS reads 16/f/CU;
//    xr on the vmem pipe (L1-resident 10 KB x-slice), depth-2 rotation.
//    Partial cur summed once per layer via component-sliced rbuf.
//
// wt layout (prep output), tile tl = l*39+f (layer0 g zero-padded):
//   wt[tl*8192 + ((ks*4 + q)*128 + n)*8 + j] = bf16(W_l[f*64 + ks*32+q*8+j][n])

#define NF      39
#define LCH     128
#define NLAYER  3
#define NFT     (NLAYER * NF)    // 117 f-tiles
#define TILE_SH 8192             // shorts per B tile (16 KB)
#define PH_T    3                // tiles per phase
#define BUF_SH  (PH_T * TILE_SH) // 24576 shorts per buffer (48 KB)
#define SLN     64               // slices per block (4 batches x 16 d)
#define NPH     (NF / PH_T)      // 13 phases per layer
#define XSTR    (NF * 16)        // 624 floats per batch row

typedef __bf16        bf16x8 __attribute__((ext_vector_type(8)));
typedef unsigned int  uint4v __attribute__((ext_vector_type(4)));
typedef float         f32x4  __attribute__((ext_vector_type(4)));

__device__ __forceinline__ unsigned short f2bf_rne(float f) {
    unsigned u = __float_as_uint(f);
    u += 0x7fffu + ((u >> 16) & 1u);
    return (unsigned short)(u >> 16);
}

// ---------------- prep: W fp32 -> bf16 frag-ready tiles in ws ----------------
__global__ void cin_prep(const float* __restrict__ W0,
                         const float* __restrict__ W1,
                         const float* __restrict__ W2,
                         unsigned short* __restrict__ wt)
{
    const int t = blockIdx.x * blockDim.x + threadIdx.x; // ((tl*2+ks)*4+q)*128 + n
    if (t >= NFT * 1024) return;
    const int n  = t & 127;
    const int q  = (t >> 7) & 3;
    const int ks = (t >> 9) & 1;
    const int tl = t >> 10;
    const int l  = tl / NF;
    const int f  = tl - l * NF;
    const float* W = (l == 0) ? W0 : (l == 1) ? W1 : W2;

    unsigned short v[8];
    #pragma unroll
    for (int j = 0; j < 8; ++j) {
        const int g = ks * 32 + q * 8 + j;
        float w = 0.0f;
        if (l == 0) { if (g < NF) w = W[(f * NF + g) * LCH + n]; }
        else        { w = W[(f * 64 + g) * LCH + n]; }
        v[j] = f2bf_rne(w);
    }
    uint4v pv;
    #pragma unroll
    for (int i = 0; i < 4; ++i)
        pv[i] = (unsigned)v[2 * i] | ((unsigned)v[2 * i + 1] << 16);
    ((uint4v*)wt)[t] = pv;   // 16B coalesced
}

// ---------------- main ----------------
__global__ __launch_bounds__(1024, 1) void cin_mfma(
    const float* __restrict__ x,
    const unsigned short* __restrict__ wt,
    const float* __restrict__ b0p,
    const float* __restrict__ b1p,
    const float* __restrict__ b2p,
    float* __restrict__ out)
{
    __shared__ __align__(16) unsigned short Bbuf[2 * BUF_SH];   // 96 KB B dbuf
    __shared__ __align__(16) unsigned short hfrag[8 * SLN * 8]; // 8 KB
    __shared__ __align__(16) float rbuf[16 * 512];              // 32 KB ks exch

    const int tid  = threadIdx.x;
    const int lane = tid & 63;
    const int w    = tid >> 6;      // wave 0..15
    const int wn   = w & 7;         // n-tile
    const int ksh  = w >> 3;        // ks-half
    const int q    = lane >> 4;     // quad 0..3
    const int c    = lane & 15;
    const int nc   = wn * 16 + c;   // this lane's output channel
    const int bb   = blockIdx.x * 4;

    // zero hfrag (covers layer-0 padding g in [39,64)): 8 KB = 512 * 16B
    if (tid < 512) {
        f32x4 z4 = {0.f, 0.f, 0.f, 0.f};
        ((f32x4*)hfrag)[tid] = z4;
    }
    __syncthreads();

    // stage layer-0 h (bf16) from x (contiguous 4*39*16 = 2496 floats)
    for (int i = tid; i < 4 * NF * 16; i += 1024) {
        const float v = x[bb * XSTR + i];
        const int lb = i / XSTR;
        const int r  = i - lb * XSTR;
        const int f  = r >> 4;
        const int d  = r & 15;
        const int sl = lb * 16 + d;
        hfrag[((f >> 3) * SLN + sl) * 8 + (f & 7)] = f2bf_rne(v);
    }

    // issue initial B staging: tiles 0..2 -> buf0 (16 waves x 1 KB per tile)
    {
        const unsigned short* src = wt + w * 512 + lane * 8;
        unsigned short* dst = Bbuf + w * 512;
        #pragma unroll
        for (int k = 0; k < PH_T; ++k)
            __builtin_amdgcn_global_load_lds((const void*)(src + k * TILE_SH),
                                             (void*)(dst + k * TILE_SH), 16, 0, 0);
    }

    // xr global base: x[(bb+mt)*624 + f*16 + q*4 .. +3], 16B aligned
    const float* xb = x + bb * XSTR + q * 4;

    __syncthreads();   // hfrag + buf0 ready

    int cb = 0;
    #pragma unroll 1
    for (int l = 0; l < NLAYER; ++l) {
        // hoist A-frags for OWN ks-half only (named, 16 VGPR)
        bf16x8 a0 = *(const bf16x8*)&hfrag[((ksh * 4 + q) * SLN + 0 * 16 + c) * 8];
        bf16x8 a1 = *(const bf16x8*)&hfrag[((ksh * 4 + q) * SLN + 1 * 16 + c) * 8];
        bf16x8 a2 = *(const bf16x8*)&hfrag[((ksh * 4 + q) * SLN + 2 * 16 + c) * 8];
        bf16x8 a3 = *(const bf16x8*)&hfrag[((ksh * 4 + q) * SLN + 3 * 16 + c) * 8];

        const f32x4 zz = {0.f, 0.f, 0.f, 0.f};
        f32x4 cur0 = zz, cur1 = zz, cur2 = zz, cur3 = zz;

        // prime xr depth-2 rotation (x is layer-invariant; f=0 and f=1)
        f32x4 xc0 = *(const f32x4*)(xb + 0 * XSTR);
        f32x4 xc1 = *(const f32x4*)(xb + 1 * XSTR);
        f32x4 xc2 = *(const f32x4*)(xb + 2 * XSTR);
        f32x4 xc3 = *(const f32x4*)(xb + 3 * XSTR);
        f32x4 xn0 = *(const f32x4*)(xb + 0 * XSTR + 16);
        f32x4 xn1 = *(const f32x4*)(xb + 1 * XSTR + 16);
        f32x4 xn2 = *(const f32x4*)(xb + 2 * XSTR + 16);
        f32x4 xn3 = *(const f32x4*)(xb + 3 * XSTR + 16);

        #pragma unroll 1
        for (int ph = 0; ph < NPH; ++ph) {
            const int tl = l * NF + ph * PH_T;

            // issue next phase's staging first (issue-early / drain-late)
            const int nb = tl + PH_T;
            if (nb < NFT) {
                const unsigned short* src = wt + (size_t)nb * TILE_SH + w * 512 + lane * 8;
                unsigned short* dst = &Bbuf[(cb ^ 1) * BUF_SH + w * 512];
                #pragma unroll
                for (int k = 0; k < PH_T; ++k)
                    __builtin_amdgcn_global_load_lds((const void*)(src + k * TILE_SH),
                                                     (void*)(dst + k * TILE_SH), 16, 0, 0);
            }

            // B-frags for this phase's 3 tiles, OWN ks-half only (from LDS)
            const unsigned short* rbq = Bbuf + cb * BUF_SH + ((ksh * 4 + q) * 128 + nc) * 8;
            const bf16x8 B0 = *(const bf16x8*)(rbq);
            const bf16x8 B1 = *(const bf16x8*)(rbq + TILE_SH);
            const bf16x8 B2 = *(const bf16x8*)(rbq + 2 * TILE_SH);

            #define F_ITER(BK, FI)                                                  \
            {                                                                       \
                f32x4 sv;                                                           \
                sv = __builtin_amdgcn_mfma_f32_16x16x32_bf16(a0, BK, zz, 0, 0, 0);  \
                _Pragma("unroll")                                                   \
                for (int r = 0; r < 4; ++r) cur0[r] = fmaf(xc0[r], sv[r], cur0[r]); \
                sv = __builtin_amdgcn_mfma_f32_16x16x32_bf16(a1, BK, zz, 0, 0, 0);  \
                _Pragma("unroll")                                                   \
                for (int r = 0; r < 4; ++r) cur1[r] = fmaf(xc1[r], sv[r], cur1[r]); \
                sv = __builtin_amdgcn_mfma_f32_16x16x32_bf16(a2, BK, zz, 0, 0, 0);  \
                _Pragma("unroll")                                                   \
                for (int r = 0; r < 4; ++r) cur2[r] = fmaf(xc2[r], sv[r], cur2[r]); \
                sv = __builtin_amdgcn_mfma_f32_16x16x32_bf16(a3, BK, zz, 0, 0, 0);  \
                _Pragma("unroll")                                                   \
                for (int r = 0; r < 4; ++r) cur3[r] = fmaf(xc3[r], sv[r], cur3[r]); \
                int fn = (FI) + 2; if (fn > NF - 1) fn = NF - 1;                    \
                xc0 = xn0; xn0 = *(const f32x4*)(xb + 0 * XSTR + fn * 16);          \
                xc1 = xn1; xn1 = *(const f32x4*)(xb + 1 * XSTR + fn * 16);          \
                xc2 = xn2; xn2 = *(const f32x4*)(xb + 2 * XSTR + fn * 16);          \
                xc3 = xn3; xn3 = *(const f32x4*)(xb + 3 * XSTR + fn * 16);          \
            }
            F_ITER(B0, ph * PH_T + 0)
            F_ITER(B1, ph * PH_T + 1)
            F_ITER(B2, ph * PH_T + 2)
            #undef F_ITER

            __syncthreads();   // drain staging + buffer handoff
            cb ^= 1;
        }

        // ---------------- layer end: ks-half reduce + epilogue ----------------
        if (ksh == 1) {
            // component-sliced: consecutive lanes -> consecutive dwords (no conflicts)
            #define RW(MT, CURV)                                                    \
            _Pragma("unroll")                                                       \
            for (int r = 0; r < 4; ++r)                                             \
                rbuf[((MT) * 4 + r) * 512 + wn * 64 + lane] = CURV[r];
            RW(0, cur0) RW(1, cur1) RW(2, cur2) RW(3, cur3)
            #undef RW
        }
        __syncthreads();
        if (ksh == 0) {
            const float* bp = (l == 0) ? b0p : (l == 1) ? b1p : b2p;
            const float bias = bp[nc];
            float v0[4], v1[4], v2[4], v3[4];
            #define RD(MT, CURV, VV)                                                \
            _Pragma("unroll")                                                       \
            for (int r = 0; r < 4; ++r)                                             \
                VV[r] = fmaxf(CURV[r] +                                             \
                              rbuf[((MT) * 4 + r) * 512 + wn * 64 + lane] +         \
                              bias, 0.f);
            RD(0, cur0, v0) RD(1, cur1, v1) RD(2, cur2, v2) RD(3, cur3, v3)
            #undef RD

            if (l < 2 && wn < 4) {
                // h channels (nc < 64): write next layer's h (C row = q*4+r)
                #define HWR(MT, VV)                                                 \
                _Pragma("unroll")                                                   \
                for (int r = 0; r < 4; ++r)                                         \
                    hfrag[((nc >> 3) * SLN + (MT) * 16 + q * 4 + r) * 8 + (nc & 7)] \
                        = f2bf_rne(VV[r]);
                HWR(0, v0) HWR(1, v1) HWR(2, v2) HWR(3, v3)
                #undef HWR
            } else {
                // direct channels: reduce over d (= q*4+r) and store
                // l==0: nc 64..127 -> out 0..63 ; l==1: nc 64..127 -> out 64..127 ;
                // l==2: nc 0..127 -> out 128..255
                const int outcol = (l == 0) ? nc - 64 : (l == 1) ? nc : 128 + nc;
                #define DST(MT, VV)                                                 \
                {                                                                   \
                    float sacc = VV[0] + VV[1] + VV[2] + VV[3];                     \
                    sacc += __shfl_xor(sacc, 16, 64);                               \
                    sacc += __shfl_xor(sacc, 32, 64);                               \
                    if (lane < 16) out[(bb + (MT)) * 256 + outcol] = sacc;          \
                }
                DST(0, v0) DST(1, v1) DST(2, v2) DST(3, v3)
                #undef DST
            }
        }
        if (l < 2) __syncthreads();   // h writes visible before next A-hoist
    }
}

extern "C" void kernel_launch(void* const* d_in, const int* in_sizes, int n_in,
                              void* d_out, int out_size, void* d_ws, size_t ws_size,
                              hipStream_t stream) {
    const float* x  = (const float*)d_in[0];
    const float* W0 = (const float*)d_in[1];
    const float* W1 = (const float*)d_in[2];
    const float* W2 = (const float*)d_in[3];
    const float* b0 = (const float*)d_in[4];
    const float* b1 = (const float*)d_in[5];
    const float* b2 = (const float*)d_in[6];
    float* out = (float*)d_out;
    unsigned short* wt = (unsigned short*)d_ws;  // 117*8192*2 B = 1.87 MB

    const int prep_threads = NFT * 1024;         // 119808
    cin_prep<<<(prep_threads + 255) / 256, 256, 0, stream>>>(W0, W1, W2, wt);
    cin_mfma<<<256, 1024, 0, stream>>>(x, wt, b0, b1, b2, out);
}

// Round 6
// 185.922 us; speedup vs baseline: 1.0052x; 1.0052x over previous
//
#include <hip/hip_runtime.h>

// CIN fused 3-layer, bf16 MFMA (R12): R10/R11 structure + pinned waves/EU.
// cur[sl,n] = sum_f x_f[sl] * S_f[sl,n],  S_f = sum_g h_g[sl] * W[f*64+g, n].
//
// R11 post-mortem: __launch_bounds__ second arg did NOT lift the 64-VGPR cap
// (R9/R10/R11 all report exactly 64; R10/R11 spill ~35 regs -> 110+ MB
// scratch HBM traffic, 127 us). The backend's occupancy heuristic targets
// 8 waves/EU regardless, even though 136 KB LDS caps the CU at 1 block
// = 4 waves/EU. Fix: pin it with amdgpu_waves_per_eu(4,4) -> 128-VGPR
// budget; demand ~100 fits, zero spill.
//
// Structure (unchanged from R10/R11):
//  - 256 blocks x 1024 thr; 16 waves = 8 n-tiles x 2 ks-halves; each wave
//    owns all 4 m-tiles, ONE un-chained MFMA per (mt,f) on its ks-half.
//    B-frag LDS reads 16 b128/f/CU (vs R8's 32: m-half waves read twice).
//  - B tiles staged to LDS once per block via global_load_lds, double
//    buffer 2 x 48 KB, issue-early/drain-late, one barrier per phase.
//  - xr on the vmem pipe (L1-resident 10 KB x-slice), depth-2 register
//    rotation in NAMED scalars -> xr LDS reads 0/f/CU.
//  - Partial cur summed once per layer via component-sliced rbuf (32 KB,
//    conflict-free). Valid by linearity of the x-scale over the g-sum.
//
// wt layout (prep output), tile tl = l*39+f (layer0 g zero-padded):
//   wt[tl*8192 + ((ks*4 + q)*128 + n)*8 + j] = bf16(W_l[f*64 + ks*32+q*8+j][n])

#define NF      39
#define LCH     128
#define NLAYER  3
#define NFT     (NLAYER * NF)    // 117 f-tiles
#define TILE_SH 8192             // shorts per B tile (16 KB)
#define PH_T    3                // tiles per phase
#define BUF_SH  (PH_T * TILE_SH) // 24576 shorts per buffer (48 KB)
#define SLN     64               // slices per block (4 batches x 16 d)
#define NPH     (NF / PH_T)      // 13 phases per layer
#define XSTR    (NF * 16)        // 624 floats per batch row

typedef __bf16        bf16x8 __attribute__((ext_vector_type(8)));
typedef unsigned int  uint4v __attribute__((ext_vector_type(4)));
typedef float         f32x4  __attribute__((ext_vector_type(4)));

__device__ __forceinline__ unsigned short f2bf_rne(float f) {
    unsigned u = __float_as_uint(f);
    u += 0x7fffu + ((u >> 16) & 1u);
    return (unsigned short)(u >> 16);
}

// ---------------- prep: W fp32 -> bf16 frag-ready tiles in ws ----------------
__global__ void cin_prep(const float* __restrict__ W0,
                         const float* __restrict__ W1,
                         const float* __restrict__ W2,
                         unsigned short* __restrict__ wt)
{
    const int t = blockIdx.x * blockDim.x + threadIdx.x; // ((tl*2+ks)*4+q)*128 + n
    if (t >= NFT * 1024) return;
    const int n  = t & 127;
    const int q  = (t >> 7) & 3;
    const int ks = (t >> 9) & 1;
    const int tl = t >> 10;
    const int l  = tl / NF;
    const int f  = tl - l * NF;
    const float* W = (l == 0) ? W0 : (l == 1) ? W1 : W2;

    unsigned short v[8];
    #pragma unroll
    for (int j = 0; j < 8; ++j) {
        const int g = ks * 32 + q * 8 + j;
        float w = 0.0f;
        if (l == 0) { if (g < NF) w = W[(f * NF + g) * LCH + n]; }
        else        { w = W[(f * 64 + g) * LCH + n]; }
        v[j] = f2bf_rne(w);
    }
    uint4v pv;
    #pragma unroll
    for (int i = 0; i < 4; ++i)
        pv[i] = (unsigned)v[2 * i] | ((unsigned)v[2 * i + 1] << 16);
    ((uint4v*)wt)[t] = pv;   // 16B coalesced
}

// ---------------- main ----------------
__global__ __launch_bounds__(1024)
__attribute__((amdgpu_waves_per_eu(4, 4)))
void cin_mfma(
    const float* __restrict__ x,
    const unsigned short* __restrict__ wt,
    const float* __restrict__ b0p,
    const float* __restrict__ b1p,
    const float* __restrict__ b2p,
    float* __restrict__ out)
{
    __shared__ __align__(16) unsigned short Bbuf[2 * BUF_SH];   // 96 KB B dbuf
    __shared__ __align__(16) unsigned short hfrag[8 * SLN * 8]; // 8 KB
    __shared__ __align__(16) float rbuf[16 * 512];              // 32 KB ks exch

    const int tid  = threadIdx.x;
    const int lane = tid & 63;
    const int w    = tid >> 6;      // wave 0..15
    const int wn   = w & 7;         // n-tile
    const int ksh  = w >> 3;        // ks-half
    const int q    = lane >> 4;     // quad 0..3
    const int c    = lane & 15;
    const int nc   = wn * 16 + c;   // this lane's output channel
    const int bb   = blockIdx.x * 4;

    // zero hfrag (covers layer-0 padding g in [39,64)): 8 KB = 512 * 16B
    if (tid < 512) {
        f32x4 z4 = {0.f, 0.f, 0.f, 0.f};
        ((f32x4*)hfrag)[tid] = z4;
    }
    __syncthreads();

    // stage layer-0 h (bf16) from x (contiguous 4*39*16 = 2496 floats)
    for (int i = tid; i < 4 * NF * 16; i += 1024) {
        const float v = x[bb * XSTR + i];
        const int lb = i / XSTR;
        const int r  = i - lb * XSTR;
        const int f  = r >> 4;
        const int d  = r & 15;
        const int sl = lb * 16 + d;
        hfrag[((f >> 3) * SLN + sl) * 8 + (f & 7)] = f2bf_rne(v);
    }

    // issue initial B staging: tiles 0..2 -> buf0 (16 waves x 1 KB per tile)
    {
        const unsigned short* src = wt + w * 512 + lane * 8;
        unsigned short* dst = Bbuf + w * 512;
        #pragma unroll
        for (int k = 0; k < PH_T; ++k)
            __builtin_amdgcn_global_load_lds((const void*)(src + k * TILE_SH),
                                             (void*)(dst + k * TILE_SH), 16, 0, 0);
    }

    // xr global base: x[(bb+mt)*624 + f*16 + q*4 .. +3], 16B aligned
    const float* xb = x + bb * XSTR + q * 4;

    __syncthreads();   // hfrag + buf0 ready

    int cb = 0;
    #pragma unroll 1
    for (int l = 0; l < NLAYER; ++l) {
        // hoist A-frags for OWN ks-half only (named, 16 VGPR)
        bf16x8 a0 = *(const bf16x8*)&hfrag[((ksh * 4 + q) * SLN + 0 * 16 + c) * 8];
        bf16x8 a1 = *(const bf16x8*)&hfrag[((ksh * 4 + q) * SLN + 1 * 16 + c) * 8];
        bf16x8 a2 = *(const bf16x8*)&hfrag[((ksh * 4 + q) * SLN + 2 * 16 + c) * 8];
        bf16x8 a3 = *(const bf16x8*)&hfrag[((ksh * 4 + q) * SLN + 3 * 16 + c) * 8];

        const f32x4 zz = {0.f, 0.f, 0.f, 0.f};
        f32x4 cur0 = zz, cur1 = zz, cur2 = zz, cur3 = zz;

        // prime xr depth-2 rotation (x is layer-invariant; f=0 and f=1)
        f32x4 xc0 = *(const f32x4*)(xb + 0 * XSTR);
        f32x4 xc1 = *(const f32x4*)(xb + 1 * XSTR);
        f32x4 xc2 = *(const f32x4*)(xb + 2 * XSTR);
        f32x4 xc3 = *(const f32x4*)(xb + 3 * XSTR);
        f32x4 xn0 = *(const f32x4*)(xb + 0 * XSTR + 16);
        f32x4 xn1 = *(const f32x4*)(xb + 1 * XSTR + 16);
        f32x4 xn2 = *(const f32x4*)(xb + 2 * XSTR + 16);
        f32x4 xn3 = *(const f32x4*)(xb + 3 * XSTR + 16);

        #pragma unroll 1
        for (int ph = 0; ph < NPH; ++ph) {
            const int tl = l * NF + ph * PH_T;

            // issue next phase's staging first (issue-early / drain-late)
            const int nb = tl + PH_T;
            if (nb < NFT) {
                const unsigned short* src = wt + (size_t)nb * TILE_SH + w * 512 + lane * 8;
                unsigned short* dst = &Bbuf[(cb ^ 1) * BUF_SH + w * 512];
                #pragma unroll
                for (int k = 0; k < PH_T; ++k)
                    __builtin_amdgcn_global_load_lds((const void*)(src + k * TILE_SH),
                                                     (void*)(dst + k * TILE_SH), 16, 0, 0);
            }

            // B-frags for this phase's 3 tiles, OWN ks-half only (from LDS)
            const unsigned short* rbq = Bbuf + cb * BUF_SH + ((ksh * 4 + q) * 128 + nc) * 8;
            const bf16x8 B0 = *(const bf16x8*)(rbq);
            const bf16x8 B1 = *(const bf16x8*)(rbq + TILE_SH);
            const bf16x8 B2 = *(const bf16x8*)(rbq + 2 * TILE_SH);

            #define F_ITER(BK, FI)                                                  \
            {                                                                       \
                f32x4 sv;                                                           \
                sv = __builtin_amdgcn_mfma_f32_16x16x32_bf16(a0, BK, zz, 0, 0, 0);  \
                _Pragma("unroll")                                                   \
                for (int r = 0; r < 4; ++r) cur0[r] = fmaf(xc0[r], sv[r], cur0[r]); \
                sv = __builtin_amdgcn_mfma_f32_16x16x32_bf16(a1, BK, zz, 0, 0, 0);  \
                _Pragma("unroll")                                                   \
                for (int r = 0; r < 4; ++r) cur1[r] = fmaf(xc1[r], sv[r], cur1[r]); \
                sv = __builtin_amdgcn_mfma_f32_16x16x32_bf16(a2, BK, zz, 0, 0, 0);  \
                _Pragma("unroll")                                                   \
                for (int r = 0; r < 4; ++r) cur2[r] = fmaf(xc2[r], sv[r], cur2[r]); \
                sv = __builtin_amdgcn_mfma_f32_16x16x32_bf16(a3, BK, zz, 0, 0, 0);  \
                _Pragma("unroll")                                                   \
                for (int r = 0; r < 4; ++r) cur3[r] = fmaf(xc3[r], sv[r], cur3[r]); \
                int fn = (FI) + 2; if (fn > NF - 1) fn = NF - 1;                    \
                xc0 = xn0; xn0 = *(const f32x4*)(xb + 0 * XSTR + fn * 16);          \
                xc1 = xn1; xn1 = *(const f32x4*)(xb + 1 * XSTR + fn * 16);          \
                xc2 = xn2; xn2 = *(const f32x4*)(xb + 2 * XSTR + fn * 16);          \
                xc3 = xn3; xn3 = *(const f32x4*)(xb + 3 * XSTR + fn * 16);          \
            }
            F_ITER(B0, ph * PH_T + 0)
            F_ITER(B1, ph * PH_T + 1)
            F_ITER(B2, ph * PH_T + 2)
            #undef F_ITER

            __syncthreads();   // drain staging + buffer handoff
            cb ^= 1;
        }

        // ---------------- layer end: ks-half reduce + epilogue ----------------
        if (ksh == 1) {
            // component-sliced: consecutive lanes -> consecutive dwords (no conflicts)
            #define RW(MT, CURV)                                                    \
            _Pragma("unroll")                                                       \
            for (int r = 0; r < 4; ++r)                                             \
                rbuf[((MT) * 4 + r) * 512 + wn * 64 + lane] = CURV[r];
            RW(0, cur0) RW(1, cur1) RW(2, cur2) RW(3, cur3)
            #undef RW
        }
        __syncthreads();
        if (ksh == 0) {
            const float* bp = (l == 0) ? b0p : (l == 1) ? b1p : b2p;
            const float bias = bp[nc];
            float v0[4], v1[4], v2[4], v3[4];
            #define RD(MT, CURV, VV)                                                \
            _Pragma("unroll")                                                       \
            for (int r = 0; r < 4; ++r)                                             \
                VV[r] = fmaxf(CURV[r] +                                             \
                              rbuf[((MT) * 4 + r) * 512 + wn * 64 + lane] +         \
                              bias, 0.f);
            RD(0, cur0, v0) RD(1, cur1, v1) RD(2, cur2, v2) RD(3, cur3, v3)
            #undef RD

            if (l < 2 && wn < 4) {
                // h channels (nc < 64): write next layer's h (C row = q*4+r)
                #define HWR(MT, VV)                                                 \
                _Pragma("unroll")                                                   \
                for (int r = 0; r < 4; ++r)                                         \
                    hfrag[((nc >> 3) * SLN + (MT) * 16 + q * 4 + r) * 8 + (nc & 7)] \
                        = f2bf_rne(VV[r]);
                HWR(0, v0) HWR(1, v1) HWR(2, v2) HWR(3, v3)
                #undef HWR
            } else {
                // direct channels: reduce over d (= q*4+r) and store
                // l==0: nc 64..127 -> out 0..63 ; l==1: nc 64..127 -> out 64..127 ;
                // l==2: nc 0..127 -> out 128..255
                const int outcol = (l == 0) ? nc - 64 : (l == 1) ? nc : 128 + nc;
                #define DST(MT, VV)                                                 \
                {                                                                   \
                    float sacc = VV[0] + VV[1] + VV[2] + VV[3];                     \
                    sacc += __shfl_xor(sacc, 16, 64);                               \
                    sacc += __shfl_xor(sacc, 32, 64);                               \
                    if (lane < 16) out[(bb + (MT)) * 256 + outcol] = sacc;          \
                }
                DST(0, v0) DST(1, v1) DST(2, v2) DST(3, v3)
                #undef DST
            }
        }
        if (l < 2) __syncthreads();   // h writes visible before next A-hoist
    }
}

extern "C" void kernel_launch(void* const* d_in, const int* in_sizes, int n_in,
                              void* d_out, int out_size, void* d_ws, size_t ws_size,
                              hipStream_t stream) {
    const float* x  = (const float*)d_in[0];
    const float* W0 = (const float*)d_in[1];
    const float* W1 = (const float*)d_in[2];
    const float* W2 = (const float*)d_in[3];
    const float* b0 = (const float*)d_in[4];
    const float* b1 = (const float*)d_in[5];
    const float* b2 = (const float*)d_in[6];
    float* out = (float*)d_out;
    unsigned short* wt = (unsigned short*)d_ws;  // 117*8192*2 B = 1.87 MB

    const int prep_threads = NFT * 1024;         // 119808
    cin_prep<<<(prep_threads + 255) / 256, 256, 0, stream>>>(W0, W1, W2, wt);
    cin_mfma<<<256, 1024, 0, stream>>>(x, wt, b0, b1, b2, out);
}

// Round 7
// 154.213 us; speedup vs baseline: 1.2118x; 1.2056x over previous
//
#include <hip/hip_runtime.h>

// CIN fused 3-layer, bf16 MFMA (R13): ks-split + global xr, 64-VGPR budget.
// cur[sl,n] = sum_f x_f[sl] * S_f[sl,n],  S_f = sum_g h_g[sl] * W[f*64+g, n].
//
// R10/R11/R12 post-mortem: three occupancy declarations ((1024,4), (1024,1),
// waves_per_eu(4,4)) all pinned at EXACTLY 64 VGPR with ~60 MB scratch spill
// traffic; R8 (same shape) allocated 52 clean. Empirical rule: this toolchain
// will not give these kernels >64 VGPRs -- DEMAND must fit 64.
// R10-12's persistent set was 64 regs before transients (xc/xn rotation = 32).
//
// R13 = R12 minus the xr rotation: F_ITER loads its 4 xr f32x4 directly from
// global (L1-resident 10 KB slice, hoistable within the phase body, covered
// by MFMA+fmaf + 4 waves/SIMD). Persistent regs ~40, peak ~60 -> no spill.
//
// Structure (as R10/R12, finally benchable):
//  - 256 blocks x 1024 thr; 16 waves = 8 n-tiles x 2 ks-halves; each wave
//    owns all 4 m-tiles, ONE un-chained MFMA per (mt,f) on its ks-half.
//    B-frag LDS reads 16 b128/f/CU (R8 m-split read each frag twice: 32).
//  - B tiles staged to LDS once per block via global_load_lds, double
//    buffer 2 x 48 KB, issue-early/drain-late, one barrier per phase.
//  - xr on the vmem pipe (L1), no persistent rotation state.
//  - Partial cur summed once per layer via component-sliced rbuf (32 KB,
//    conflict-free). Valid by linearity of the x-scale over the g-sum.
//
// wt layout (prep output), tile tl = l*39+f (layer0 g zero-padded):
//   wt[tl*8192 + ((ks*4 + q)*128 + n)*8 + j] = bf16(W_l[f*64 + ks*32+q*8+j][n])

#define NF      39
#define LCH     128
#define NLAYER  3
#define NFT     (NLAYER * NF)    // 117 f-tiles
#define TILE_SH 8192             // shorts per B tile (16 KB)
#define PH_T    3                // tiles per phase
#define BUF_SH  (PH_T * TILE_SH) // 24576 shorts per buffer (48 KB)
#define SLN     64               // slices per block (4 batches x 16 d)
#define NPH     (NF / PH_T)      // 13 phases per layer
#define XSTR    (NF * 16)        // 624 floats per batch row

typedef __bf16        bf16x8 __attribute__((ext_vector_type(8)));
typedef unsigned int  uint4v __attribute__((ext_vector_type(4)));
typedef float         f32x4  __attribute__((ext_vector_type(4)));

__device__ __forceinline__ unsigned short f2bf_rne(float f) {
    unsigned u = __float_as_uint(f);
    u += 0x7fffu + ((u >> 16) & 1u);
    return (unsigned short)(u >> 16);
}

// ---------------- prep: W fp32 -> bf16 frag-ready tiles in ws ----------------
__global__ void cin_prep(const float* __restrict__ W0,
                         const float* __restrict__ W1,
                         const float* __restrict__ W2,
                         unsigned short* __restrict__ wt)
{
    const int t = blockIdx.x * blockDim.x + threadIdx.x; // ((tl*2+ks)*4+q)*128 + n
    if (t >= NFT * 1024) return;
    const int n  = t & 127;
    const int q  = (t >> 7) & 3;
    const int ks = (t >> 9) & 1;
    const int tl = t >> 10;
    const int l  = tl / NF;
    const int f  = tl - l * NF;
    const float* W = (l == 0) ? W0 : (l == 1) ? W1 : W2;

    unsigned short v[8];
    #pragma unroll
    for (int j = 0; j < 8; ++j) {
        const int g = ks * 32 + q * 8 + j;
        float w = 0.0f;
        if (l == 0) { if (g < NF) w = W[(f * NF + g) * LCH + n]; }
        else        { w = W[(f * 64 + g) * LCH + n]; }
        v[j] = f2bf_rne(w);
    }
    uint4v pv;
    #pragma unroll
    for (int i = 0; i < 4; ++i)
        pv[i] = (unsigned)v[2 * i] | ((unsigned)v[2 * i + 1] << 16);
    ((uint4v*)wt)[t] = pv;   // 16B coalesced
}

// ---------------- main ----------------
__global__ __launch_bounds__(1024, 4) void cin_mfma(
    const float* __restrict__ x,
    const unsigned short* __restrict__ wt,
    const float* __restrict__ b0p,
    const float* __restrict__ b1p,
    const float* __restrict__ b2p,
    float* __restrict__ out)
{
    __shared__ __align__(16) unsigned short Bbuf[2 * BUF_SH];   // 96 KB B dbuf
    __shared__ __align__(16) unsigned short hfrag[8 * SLN * 8]; // 8 KB
    __shared__ __align__(16) float rbuf[16 * 512];              // 32 KB ks exch

    const int tid  = threadIdx.x;
    const int lane = tid & 63;
    const int w    = tid >> 6;      // wave 0..15
    const int wn   = w & 7;         // n-tile
    const int ksh  = w >> 3;        // ks-half
    const int q    = lane >> 4;     // quad 0..3
    const int c    = lane & 15;
    const int nc   = wn * 16 + c;   // this lane's output channel
    const int bb   = blockIdx.x * 4;

    // zero hfrag (covers layer-0 padding g in [39,64)): 8 KB = 512 * 16B
    if (tid < 512) {
        f32x4 z4 = {0.f, 0.f, 0.f, 0.f};
        ((f32x4*)hfrag)[tid] = z4;
    }
    __syncthreads();

    // stage layer-0 h (bf16) from x (contiguous 4*39*16 = 2496 floats)
    for (int i = tid; i < 4 * NF * 16; i += 1024) {
        const float v = x[bb * XSTR + i];
        const int lb = i / XSTR;
        const int r  = i - lb * XSTR;
        const int f  = r >> 4;
        const int d  = r & 15;
        const int sl = lb * 16 + d;
        hfrag[((f >> 3) * SLN + sl) * 8 + (f & 7)] = f2bf_rne(v);
    }

    // issue initial B staging: tiles 0..2 -> buf0 (16 waves x 1 KB per tile)
    {
        const unsigned short* src = wt + w * 512 + lane * 8;
        unsigned short* dst = Bbuf + w * 512;
        #pragma unroll
        for (int k = 0; k < PH_T; ++k)
            __builtin_amdgcn_global_load_lds((const void*)(src + k * TILE_SH),
                                             (void*)(dst + k * TILE_SH), 16, 0, 0);
    }

    // xr global base: x[(bb+mt)*624 + f*16 + q*4 .. +3], 16B aligned
    const float* xb = x + bb * XSTR + q * 4;

    __syncthreads();   // hfrag + buf0 ready

    int cb = 0;
    #pragma unroll 1
    for (int l = 0; l < NLAYER; ++l) {
        // hoist A-frags for OWN ks-half only (named, 16 VGPR)
        bf16x8 a0 = *(const bf16x8*)&hfrag[((ksh * 4 + q) * SLN + 0 * 16 + c) * 8];
        bf16x8 a1 = *(const bf16x8*)&hfrag[((ksh * 4 + q) * SLN + 1 * 16 + c) * 8];
        bf16x8 a2 = *(const bf16x8*)&hfrag[((ksh * 4 + q) * SLN + 2 * 16 + c) * 8];
        bf16x8 a3 = *(const bf16x8*)&hfrag[((ksh * 4 + q) * SLN + 3 * 16 + c) * 8];

        const f32x4 zz = {0.f, 0.f, 0.f, 0.f};
        f32x4 cur0 = zz, cur1 = zz, cur2 = zz, cur3 = zz;

        #pragma unroll 1
        for (int ph = 0; ph < NPH; ++ph) {
            const int tl = l * NF + ph * PH_T;

            // issue next phase's staging first (issue-early / drain-late)
            const int nb = tl + PH_T;
            if (nb < NFT) {
                const unsigned short* src = wt + (size_t)nb * TILE_SH + w * 512 + lane * 8;
                unsigned short* dst = &Bbuf[(cb ^ 1) * BUF_SH + w * 512];
                #pragma unroll
                for (int k = 0; k < PH_T; ++k)
                    __builtin_amdgcn_global_load_lds((const void*)(src + k * TILE_SH),
                                                     (void*)(dst + k * TILE_SH), 16, 0, 0);
            }

            // B-frags for this phase's 3 tiles, OWN ks-half only (from LDS)
            const unsigned short* rbq = Bbuf + cb * BUF_SH + ((ksh * 4 + q) * 128 + nc) * 8;
            const bf16x8 B0 = *(const bf16x8*)(rbq);
            const bf16x8 B1 = *(const bf16x8*)(rbq + TILE_SH);
            const bf16x8 B2 = *(const bf16x8*)(rbq + 2 * TILE_SH);

            const int f0 = ph * PH_T;
            // per-f xr loaded directly from global (L1-hit); no persistent
            // rotation state -- keeps peak VGPR under the empirical 64 wall.
            #define F_ITER(BK, FI)                                                  \
            {                                                                       \
                const f32x4 xr0 = *(const f32x4*)(xb + 0 * XSTR + (FI) * 16);       \
                const f32x4 xr1 = *(const f32x4*)(xb + 1 * XSTR + (FI) * 16);       \
                const f32x4 xr2 = *(const f32x4*)(xb + 2 * XSTR + (FI) * 16);       \
                const f32x4 xr3 = *(const f32x4*)(xb + 3 * XSTR + (FI) * 16);       \
                f32x4 sv;                                                           \
                sv = __builtin_amdgcn_mfma_f32_16x16x32_bf16(a0, BK, zz, 0, 0, 0);  \
                _Pragma("unroll")                                                   \
                for (int r = 0; r < 4; ++r) cur0[r] = fmaf(xr0[r], sv[r], cur0[r]); \
                sv = __builtin_amdgcn_mfma_f32_16x16x32_bf16(a1, BK, zz, 0, 0, 0);  \
                _Pragma("unroll")                                                   \
                for (int r = 0; r < 4; ++r) cur1[r] = fmaf(xr1[r], sv[r], cur1[r]); \
                sv = __builtin_amdgcn_mfma_f32_16x16x32_bf16(a2, BK, zz, 0, 0, 0);  \
                _Pragma("unroll")                                                   \
                for (int r = 0; r < 4; ++r) cur2[r] = fmaf(xr2[r], sv[r], cur2[r]); \
                sv = __builtin_amdgcn_mfma_f32_16x16x32_bf16(a3, BK, zz, 0, 0, 0);  \
                _Pragma("unroll")                                                   \
                for (int r = 0; r < 4; ++r) cur3[r] = fmaf(xr3[r], sv[r], cur3[r]); \
            }
            F_ITER(B0, f0 + 0)
            F_ITER(B1, f0 + 1)
            F_ITER(B2, f0 + 2)
            #undef F_ITER

            __syncthreads();   // drain staging + buffer handoff
            cb ^= 1;
        }

        // ---------------- layer end: ks-half reduce + epilogue ----------------
        if (ksh == 1) {
            // component-sliced: consecutive lanes -> consecutive dwords (no conflicts)
            #define RW(MT, CURV)                                                    \
            _Pragma("unroll")                                                       \
            for (int r = 0; r < 4; ++r)                                             \
                rbuf[((MT) * 4 + r) * 512 + wn * 64 + lane] = CURV[r];
            RW(0, cur0) RW(1, cur1) RW(2, cur2) RW(3, cur3)
            #undef RW
        }
        __syncthreads();
        if (ksh == 0) {
            const float* bp = (l == 0) ? b0p : (l == 1) ? b1p : b2p;
            const float bias = bp[nc];
            float v0[4], v1[4], v2[4], v3[4];
            #define RD(MT, CURV, VV)                                                \
            _Pragma("unroll")                                                       \
            for (int r = 0; r < 4; ++r)                                             \
                VV[r] = fmaxf(CURV[r] +                                             \
                              rbuf[((MT) * 4 + r) * 512 + wn * 64 + lane] +         \
                              bias, 0.f);
            RD(0, cur0, v0) RD(1, cur1, v1) RD(2, cur2, v2) RD(3, cur3, v3)
            #undef RD

            if (l < 2 && wn < 4) {
                // h channels (nc < 64): write next layer's h (C row = q*4+r)
                #define HWR(MT, VV)                                                 \
                _Pragma("unroll")                                                   \
                for (int r = 0; r < 4; ++r)                                         \
                    hfrag[((nc >> 3) * SLN + (MT) * 16 + q * 4 + r) * 8 + (nc & 7)] \
                        = f2bf_rne(VV[r]);
                HWR(0, v0) HWR(1, v1) HWR(2, v2) HWR(3, v3)
                #undef HWR
            } else {
                // direct channels: reduce over d (= q*4+r) and store
                // l==0: nc 64..127 -> out 0..63 ; l==1: nc 64..127 -> out 64..127 ;
                // l==2: nc 0..127 -> out 128..255
                const int outcol = (l == 0) ? nc - 64 : (l == 1) ? nc : 128 + nc;
                #define DST(MT, VV)                                                 \
                {                                                                   \
                    float sacc = VV[0] + VV[1] + VV[2] + VV[3];                     \
                    sacc += __shfl_xor(sacc, 16, 64);                               \
                    sacc += __shfl_xor(sacc, 32, 64);                               \
                    if (lane < 16) out[(bb + (MT)) * 256 + outcol] = sacc;          \
                }
                DST(0, v0) DST(1, v1) DST(2, v2) DST(3, v3)
                #undef DST
            }
        }
        if (l < 2) __syncthreads();   // h writes visible before next A-hoist
    }
}

extern "C" void kernel_launch(void* const* d_in, const int* in_sizes, int n_in,
                              void* d_out, int out_size, void* d_ws, size_t ws_size,
                              hipStream_t stream) {
    const float* x  = (const float*)d_in[0];
    const float* W0 = (const float*)d_in[1];
    const float* W1 = (const float*)d_in[2];
    const float* W2 = (const float*)d_in[3];
    const float* b0 = (const float*)d_in[4];
    const float* b1 = (const float*)d_in[5];
    const float* b2 = (const float*)d_in[6];
    float* out = (float*)d_out;
    unsigned short* wt = (unsigned short*)d_ws;  // 117*8192*2 B = 1.87 MB

    const int prep_threads = NFT * 1024;         // 119808
    cin_prep<<<(prep_threads + 255) / 256, 256, 0, stream>>>(W0, W1, W2, wt);
    cin_mfma<<<256, 1024, 0, stream>>>(x, wt, b0, b1, b2, out);
}